// Round 9
// baseline (610.449 us; speedup 1.0000x reference)
//
#include <hip/hip_runtime.h>

#define NN 50000
#define NE 800000
#define CC 128
#define NL 3

typedef short bf16x8 __attribute__((ext_vector_type(8)));
typedef float f32x4 __attribute__((ext_vector_type(4)));
union U16 { uint4 u; bf16x8 v; };

__device__ __forceinline__ float b2f(unsigned short u) {
  return __uint_as_float(((unsigned int)u) << 16);
}
__device__ __forceinline__ unsigned short f2b(float f) {
  unsigned int x = __float_as_uint(f);
  x += 0x7fffu + ((x >> 16) & 1u);   // round-to-nearest-even
  return (unsigned short)(x >> 16);
}

// flags[0] = 1 if float tensors are bf16, 0 if f32.
// flags[1] = 1 if edge_index is int64 (odd 32-bit words all zero), 0 if int32.
__global__ void k_flags(const unsigned short* __restrict__ x,
                        const int* __restrict__ ei, int* __restrict__ flags) {
  __shared__ int cnt, any;
  if (threadIdx.x == 0) { cnt = 0; any = 0; }
  __syncthreads();
  if (threadIdx.x < 128) {
    unsigned short u = x[2 * threadIdx.x];
    int ex = (u >> 7) & 0xFF;
    if (ex >= 0x70 && ex <= 0x8F) atomicAdd(&cnt, 1);
  }
  if (ei[2 * threadIdx.x + 1] != 0) atomicOr(&any, 1);
  __syncthreads();
  if (threadIdx.x == 0) {
    flags[0] = (cnt >= 64) ? 1 : 0;
    flags[1] = (any == 0) ? 1 : 0;
  }
}

__device__ __forceinline__ int eidx(const int* ei, int row, int e, int f64) {
  return f64 ? ei[2 * ((size_t)row * NE + e)] : ei[(size_t)row * NE + e];
}

// ---- x -> bf16 workspace; no-op in bf16 mode (layer 0 reads d_in[0] direct) ----
__global__ __launch_bounds__(256) void k_cvt_x(const void* __restrict__ xin,
                                               unsigned short* __restrict__ xb,
                                               const int* __restrict__ flags) {
  if (flags[0]) return;
  int i = blockIdx.x * 256 + threadIdx.x;   // NN*CC/8 threads exactly
  const float4 a = ((const float4*)xin)[2 * i];
  const float4 b = ((const float4*)xin)[2 * i + 1];
  uint4 o;
  o.x = (unsigned)f2b(a.x) | ((unsigned)f2b(a.y) << 16);
  o.y = (unsigned)f2b(a.z) | ((unsigned)f2b(a.w) << 16);
  o.z = (unsigned)f2b(b.x) | ((unsigned)f2b(b.y) << 16);
  o.w = (unsigned)f2b(b.z) | ((unsigned)f2b(b.w) << 16);
  ((uint4*)xb)[i] = o;
}

// ---- params: W transpose->bf16 (wt[l][n][k]), bias/emlp -> f32 ----
__global__ __launch_bounds__(256) void k_cvt_par(const void* lw, const void* lb,
                                                 const void* emw, const void* emb,
                                                 unsigned short* __restrict__ wt,
                                                 float* lbf, float* emwf, float* embf,
                                                 const int* __restrict__ flags) {
  int i = blockIdx.x * 256 + threadIdx.x;
  const int bf = flags[0];
  if (i < NL * CC * CC) {
    unsigned short v = bf ? ((const unsigned short*)lw)[i]
                          : f2b(((const float*)lw)[i]);
    const int l = i >> 14, r = i & 16383, k = r >> 7, n = r & 127;
    wt[l * 16384 + n * 128 + k] = v;
  }
  if (i < NL * CC)
    lbf[i] = bf ? b2f(((const unsigned short*)lb)[i]) : ((const float*)lb)[i];
  if (i < NL * 8)
    emwf[i] = bf ? b2f(((const unsigned short*)emw)[i]) : ((const float*)emw)[i];
  if (i < NL)
    embf[i] = bf ? b2f(((const unsigned short*)emb)[i]) : ((const float*)emb)[i];
}

// ---- CSR build: histogram of dst ----
__global__ __launch_bounds__(256) void k_hist(const int* __restrict__ ei,
                                              int* __restrict__ deg,
                                              const int* __restrict__ flags) {
  int e = blockIdx.x * 256 + threadIdx.x;
  if (e >= NE) return;
  atomicAdd(&deg[eidx(ei, 1, e, flags[1])], 1);
}

// ---- 3-phase device-wide exclusive scan over deg[NN] ----
#define NI4 (NN / 4)
#define SCAN_BLKS ((NI4 + 255) / 256)   // 49
__global__ __launch_bounds__(256) void k_scan1(const int* __restrict__ deg,
                                               int* __restrict__ offs,
                                               int* __restrict__ bsum) {
  __shared__ int ls[256];
  const int t = threadIdx.x;
  const int g = blockIdx.x * 256 + t;
  int4 d = make_int4(0, 0, 0, 0);
  if (g < NI4) d = ((const int4*)deg)[g];
  const int s = d.x + d.y + d.z + d.w;
  ls[t] = s;
  __syncthreads();
#pragma unroll
  for (int off = 1; off < 256; off <<= 1) {
    int tmp = (t >= off) ? ls[t - off] : 0;
    __syncthreads();
    ls[t] += tmp;
    __syncthreads();
  }
  const int excl = ls[t] - s;
  if (g < NI4) {
    int4 o;
    o.x = excl; o.y = o.x + d.x; o.z = o.y + d.y; o.w = o.z + d.z;
    ((int4*)offs)[g] = o;
  }
  if (t == 255) bsum[blockIdx.x] = ls[255];
}

__global__ void k_scan2(const int* __restrict__ bsum, int* __restrict__ bbase,
                        int* __restrict__ offs) {
  if (threadIdx.x == 0) {
    int run = 0;
    for (int b = 0; b < SCAN_BLKS; ++b) { bbase[b] = run; run += bsum[b]; }
    offs[NN] = run;
  }
}

__global__ __launch_bounds__(256) void k_scan3(int* __restrict__ offs,
                                               int* __restrict__ cursor,
                                               const int* __restrict__ bbase) {
  const int g = blockIdx.x * 256 + threadIdx.x;
  if (g >= NI4) return;
  const int base = bbase[blockIdx.x];
  int4 o = ((int4*)offs)[g];
  o.x += base; o.y += base; o.z += base; o.w += base;
  ((int4*)offs)[g] = o;
  ((int4*)cursor)[g] = o;
}

// ---- CSR fill + all-layer edge weights, one scattered 16B store per edge:
//      esrt[pos] = (src, w0, w1, w2) with wl = softplus(ea . ew_l + eb_l)
__global__ __launch_bounds__(256) void k_fill2(const int* __restrict__ ei,
                                               const void* __restrict__ ea,
                                               const float* __restrict__ emwf,
                                               const float* __restrict__ embf,
                                               int* __restrict__ cursor,
                                               uint4* __restrict__ esrt,
                                               const int* __restrict__ flags) {
  int e = blockIdx.x * 256 + threadIdx.x;
  if (e >= NE) return;
  float a[8];
  if (flags[0]) {
    const uint4 v = ((const uint4*)ea)[e];
    unsigned int p[4] = {v.x, v.y, v.z, v.w};
#pragma unroll
    for (int q = 0; q < 4; ++q) {
      a[2 * q]     = __uint_as_float(p[q] << 16);
      a[2 * q + 1] = __uint_as_float(p[q] & 0xffff0000u);
    }
  } else {
    const float4 v0 = ((const float4*)ea)[2 * e];
    const float4 v1 = ((const float4*)ea)[2 * e + 1];
    a[0] = v0.x; a[1] = v0.y; a[2] = v0.z; a[3] = v0.w;
    a[4] = v1.x; a[5] = v1.y; a[6] = v1.z; a[7] = v1.w;
  }
  float w[NL];
#pragma unroll
  for (int l = 0; l < NL; ++l) {
    float z = embf[l];
#pragma unroll
    for (int k = 0; k < 8; ++k) z += a[k] * emwf[l * 8 + k];
    w[l] = (z > 20.f) ? z : log1pf(expf(z));
  }
  const int f64 = flags[1];
  const int d = eidx(ei, 1, e, f64);
  const int s = eidx(ei, 0, e, f64);
  const int pos = atomicAdd(&cursor[d], 1);
  esrt[pos] = make_uint4((unsigned)s, __float_as_uint(w[0]),
                         __float_as_uint(w[1]), __float_as_uint(w[2]));
}

// ---- fused layer: gather into LDS A-tile + MFMA gemm + epilogue ----
// 512 threads (8 waves), 64 rows/block. Gather is software-pipelined: two
// 4-edge batches rotate so one batch's loads are in flight while the other
// batch's FMAs execute.
#define LPAD 136

struct Batch {
  uint4 p0, p1, p2, p3;
  unsigned v0, v1, v2, v3;
};

__device__ __forceinline__ void load_batch(Batch& b, const uint4* __restrict__ esrt,
                                           const unsigned short* xc, int j, int c) {
  b.p0 = esrt[j]; b.p1 = esrt[j + 1]; b.p2 = esrt[j + 2]; b.p3 = esrt[j + 3];
  b.v0 = *(const unsigned*)&xc[(size_t)b.p0.x * CC + c];
  b.v1 = *(const unsigned*)&xc[(size_t)b.p1.x * CC + c];
  b.v2 = *(const unsigned*)&xc[(size_t)b.p2.x * CC + c];
  b.v3 = *(const unsigned*)&xc[(size_t)b.p3.x * CC + c];
}

__device__ __forceinline__ void accum_batch(const Batch& b, int layer,
                                            float& ax, float& ay, float& sw) {
  const float w0 = __uint_as_float(layer == 0 ? b.p0.y : (layer == 1 ? b.p0.z : b.p0.w));
  const float w1 = __uint_as_float(layer == 0 ? b.p1.y : (layer == 1 ? b.p1.z : b.p1.w));
  const float w2 = __uint_as_float(layer == 0 ? b.p2.y : (layer == 1 ? b.p2.z : b.p2.w));
  const float w3 = __uint_as_float(layer == 0 ? b.p3.y : (layer == 1 ? b.p3.z : b.p3.w));
  ax += w0 * __uint_as_float(b.v0 << 16) + w1 * __uint_as_float(b.v1 << 16)
      + w2 * __uint_as_float(b.v2 << 16) + w3 * __uint_as_float(b.v3 << 16);
  ay += w0 * __uint_as_float(b.v0 & 0xffff0000u) + w1 * __uint_as_float(b.v1 & 0xffff0000u)
      + w2 * __uint_as_float(b.v2 & 0xffff0000u) + w3 * __uint_as_float(b.v3 & 0xffff0000u);
  sw += w0 + w1 + w2 + w3;
}

__global__ __launch_bounds__(512) void k_layer(const int* __restrict__ offs,
                                               const uint4* __restrict__ esrt,
                                               const unsigned short* xc_,
                                               const unsigned short* alt,
                                               int sel, int layer,
                                               const unsigned short* __restrict__ wt,
                                               const float* __restrict__ lbf,
                                               unsigned short* __restrict__ xn,
                                               void* outp, int last,
                                               const int* __restrict__ flags) {
  const unsigned short* xc = (sel && flags[0]) ? alt : xc_;
  __shared__ unsigned short shA[64 * LPAD];    // 17408 B
  __shared__ unsigned short shB[128 * LPAD];   // 34816 B
  const int rb = blockIdx.x * 64;
  const unsigned short* wtl = wt + (size_t)layer * CC * CC;

  // stage B = W_t (128 x 128 bf16)
  for (int u = threadIdx.x; u < 2048; u += 512) {
    const int row = u >> 4, q = u & 15;
    *(uint4*)&shB[row * LPAD + q * 8] = *(const uint4*)&wtl[row * 128 + q * 8];
  }

  const int w = threadIdx.x >> 6;   // wave 0..7
  const int l = threadIdx.x & 63;
  const int c = l * 2;              // channel pair for gather

  // ---- gather phase: wave w fills shA rows w*8 .. w*8+7 (pipelined) ----
  for (int i = 0; i < 8; ++i) {
    const int row = w * 8 + i;
    const int node = rb + row;
    float ax = 0.f, ay = 0.f, sw = 0.f;
    if (node < NN) {
      int j = offs[node];
      const int j1 = offs[node + 1];
      const int nb = (j1 - j) >> 2;     // full 4-edge batches
      if (nb > 0) {
        Batch cur, nxt;
        load_batch(cur, esrt, xc, j, c);
        for (int b = 1; b < nb; ++b) {
          load_batch(nxt, esrt, xc, j + b * 4, c);   // in flight during accum
          accum_batch(cur, layer, ax, ay, sw);
          cur = nxt;
        }
        accum_batch(cur, layer, ax, ay, sw);
        j += nb * 4;
      }
      for (; j < j1; ++j) {
        const uint4 p0 = esrt[j];
        const float w0 = __uint_as_float(layer == 0 ? p0.y : (layer == 1 ? p0.z : p0.w));
        const unsigned v0 = *(const unsigned*)&xc[(size_t)p0.x * CC + c];
        ax += w0 * __uint_as_float(v0 << 16);
        ay += w0 * __uint_as_float(v0 & 0xffff0000u);
        sw += w0;
      }
      const unsigned xi = *(const unsigned*)&xc[(size_t)node * CC + c];
      ax -= sw * __uint_as_float(xi << 16);
      ay -= sw * __uint_as_float(xi & 0xffff0000u);
    }
    *(unsigned*)&shA[row * LPAD + c] = (unsigned)f2b(ax) | ((unsigned)f2b(ay) << 16);
  }
  __syncthreads();

  // ---- MFMA phase: wave w -> row-tile rt=w&3 (16 rows), col-half ch=w>>2 ----
  const int rt = w & 3, ch = w >> 2;
  const int lr = l & 15;
  const int lk = (l >> 4) * 8;

  U16 afr[4];
#pragma unroll
  for (int kk = 0; kk < 4; ++kk)
    afr[kk].u = *(const uint4*)&shA[(rt * 16 + lr) * LPAD + kk * 32 + lk];

  f32x4 acc[4];
#pragma unroll
  for (int t = 0; t < 4; ++t) {
    acc[t] = (f32x4){0.f, 0.f, 0.f, 0.f};
    const int tc = ch * 4 + t;   // col-tile 0..7
#pragma unroll
    for (int kk = 0; kk < 4; ++kk) {
      U16 bfr;
      bfr.u = *(const uint4*)&shB[(tc * 16 + lr) * LPAD + kk * 32 + lk];
      acc[t] = __builtin_amdgcn_mfma_f32_16x16x32_bf16(afr[kk].v, bfr.v, acc[t], 0, 0, 0);
    }
  }

  // row-tiles are shared between wave pairs (rt, rt+4): wait for all MFMA A-reads
  __syncthreads();

  const float* lbp = lbf + layer * CC;
#pragma unroll
  for (int t = 0; t < 4; ++t) {
    const int tc = ch * 4 + t;
    const float bv = lbp[tc * 16 + lr];
#pragma unroll
    for (int r = 0; r < 4; ++r) {
      const int tr = (l >> 4) * 4 + r;   // C/D: row = quad*4 + reg
      shA[(rt * 16 + tr) * LPAD + tc * 16 + lr] = f2b(acc[t][r] + bv);
    }
  }
  // wave-private readback (wave wrote rows rt*16..+15, cols ch*64..+63)
  const int isbf = flags[0];
#pragma unroll
  for (int p = 0; p < 4; ++p) {
    const int idx = p * 64 + l;         // 256 uint2-groups: 16 rows x 16 segs
    const int row = idx >> 4, seg = idx & 15;
    const int gr = rb + rt * 16 + row;
    if (gr >= NN) continue;
    const uint2 yv = *(const uint2*)&shA[(rt * 16 + row) * LPAD + ch * 64 + seg * 4];
    float y0 = __uint_as_float(yv.x << 16);
    float y1 = __uint_as_float(yv.x & 0xffff0000u);
    float y2 = __uint_as_float(yv.y << 16);
    float y3 = __uint_as_float(yv.y & 0xffff0000u);
    const size_t off = (size_t)gr * CC + ch * 64 + seg * 4;
    if (!last) {
      const uint2 rv = *(const uint2*)&xc[off];
      y0 = fmaxf(y0, 0.f) + __uint_as_float(rv.x << 16);
      y1 = fmaxf(y1, 0.f) + __uint_as_float(rv.x & 0xffff0000u);
      y2 = fmaxf(y2, 0.f) + __uint_as_float(rv.y << 16);
      y3 = fmaxf(y3, 0.f) + __uint_as_float(rv.y & 0xffff0000u);
      *(uint2*)&xn[off] = make_uint2((unsigned)f2b(y0) | ((unsigned)f2b(y1) << 16),
                                     (unsigned)f2b(y2) | ((unsigned)f2b(y3) << 16));
    } else if (isbf) {
      *(uint2*)&((unsigned short*)outp)[off] = yv;
    } else {
      *(float4*)&((float*)outp)[off] = make_float4(y0, y1, y2, y3);
    }
  }
}

extern "C" void kernel_launch(void* const* d_in, const int* in_sizes, int n_in,
                              void* d_out, int out_size, void* d_ws, size_t ws_size,
                              hipStream_t stream) {
  const unsigned short* x0 = (const unsigned short*)d_in[0];
  const int* ei = (const int*)d_in[1];

  // workspace: xb0,xb1 bf16 | wt bf16 | esrt uint4[NE] | deg/offs/cursor |
  //            bsum/bbase | lbf/emwf/embf f32 | flags   (~40 MB)
  const size_t nbuf = (size_t)NN * CC;
  unsigned short* xb0 = (unsigned short*)d_ws;
  unsigned short* xb1 = xb0 + nbuf;
  unsigned short* wt = xb1 + nbuf;
  uint4* esrt = (uint4*)(wt + (size_t)NL * CC * CC);
  int* deg = (int*)(esrt + NE);
  int* offs = deg + NN;
  int* cursor = offs + NN + 4;
  int* bsum = cursor + NN;
  int* bbase = bsum + 64;
  float* lbf = (float*)(bbase + 64);
  float* emwf = lbf + (size_t)NL * CC;
  float* embf = emwf + NL * 8;
  int* flags = (int*)(embf + NL);
  const size_t need = (size_t)((char*)(flags + 2) - (char*)d_ws);
  if (ws_size < need) {
    hipMemsetAsync(d_out, 0, (size_t)out_size * 2, stream);
    return;
  }

  k_flags<<<1, 256, 0, stream>>>(x0, ei, flags);
  k_cvt_x<<<(NN * CC / 8) / 256, 256, 0, stream>>>(d_in[0], xb0, flags);
  k_cvt_par<<<(NL * CC * CC + 255) / 256, 256, 0, stream>>>(
      d_in[3], d_in[4], d_in[5], d_in[6], wt, lbf, emwf, embf, flags);

  hipMemsetAsync(deg, 0, NN * sizeof(int), stream);
  k_hist<<<(NE + 255) / 256, 256, 0, stream>>>(ei, deg, flags);
  k_scan1<<<SCAN_BLKS, 256, 0, stream>>>(deg, offs, bsum);
  k_scan2<<<1, 64, 0, stream>>>(bsum, bbase, offs);
  k_scan3<<<SCAN_BLKS, 256, 0, stream>>>(offs, cursor, bbase);
  k_fill2<<<(NE + 255) / 256, 256, 0, stream>>>(ei, d_in[2], emwf, embf,
                                                cursor, esrt, flags);

  const int nblk = (NN + 63) / 64;
  unsigned short* xc = xb0;
  unsigned short* xn = xb1;
  for (int layer = 0; layer < NL; ++layer) {
    const int sel = (layer == 0) ? 1 : 0;
    k_layer<<<nblk, 512, 0, stream>>>(offs, esrt, xc, x0, sel, layer,
                                      wt, lbf, xn, d_out,
                                      layer == NL - 1 ? 1 : 0, flags);
    unsigned short* t = xc; xc = xn; xn = t;
  }
}

// Round 10
// 363.027 us; speedup vs baseline: 1.6816x; 1.6816x over previous
//
#include <hip/hip_runtime.h>

#define NN 50000
#define NE 800000
#define CC 128
#define NL 3

typedef short bf16x8 __attribute__((ext_vector_type(8)));
typedef float f32x4 __attribute__((ext_vector_type(4)));
union U16 { uint4 u; bf16x8 v; };

__device__ __forceinline__ float b2f(unsigned short u) {
  return __uint_as_float(((unsigned int)u) << 16);
}
__device__ __forceinline__ unsigned short f2b(float f) {
  unsigned int x = __float_as_uint(f);
  x += 0x7fffu + ((x >> 16) & 1u);   // round-to-nearest-even
  return (unsigned short)(x >> 16);
}

// flags[0] = 1 if float tensors are bf16, 0 if f32.
// flags[1] = 1 if edge_index is int64 (odd 32-bit words all zero), 0 if int32.
__global__ void k_flags(const unsigned short* __restrict__ x,
                        const int* __restrict__ ei, int* __restrict__ flags) {
  __shared__ int cnt, any;
  if (threadIdx.x == 0) { cnt = 0; any = 0; }
  __syncthreads();
  if (threadIdx.x < 128) {
    unsigned short u = x[2 * threadIdx.x];
    int ex = (u >> 7) & 0xFF;
    if (ex >= 0x70 && ex <= 0x8F) atomicAdd(&cnt, 1);
  }
  if (ei[2 * threadIdx.x + 1] != 0) atomicOr(&any, 1);
  __syncthreads();
  if (threadIdx.x == 0) {
    flags[0] = (cnt >= 64) ? 1 : 0;
    flags[1] = (any == 0) ? 1 : 0;
  }
}

__device__ __forceinline__ int eidx(const int* ei, int row, int e, int f64) {
  return f64 ? ei[2 * ((size_t)row * NE + e)] : ei[(size_t)row * NE + e];
}

// ---- x -> bf16 workspace; no-op in bf16 mode (layer 0 reads d_in[0] direct) ----
__global__ __launch_bounds__(256) void k_cvt_x(const void* __restrict__ xin,
                                               unsigned short* __restrict__ xb,
                                               const int* __restrict__ flags) {
  if (flags[0]) return;
  int i = blockIdx.x * 256 + threadIdx.x;   // NN*CC/8 threads exactly
  const float4 a = ((const float4*)xin)[2 * i];
  const float4 b = ((const float4*)xin)[2 * i + 1];
  uint4 o;
  o.x = (unsigned)f2b(a.x) | ((unsigned)f2b(a.y) << 16);
  o.y = (unsigned)f2b(a.z) | ((unsigned)f2b(a.w) << 16);
  o.z = (unsigned)f2b(b.x) | ((unsigned)f2b(b.y) << 16);
  o.w = (unsigned)f2b(b.z) | ((unsigned)f2b(b.w) << 16);
  ((uint4*)xb)[i] = o;
}

// ---- params: W transpose->bf16 (wt[l][n][k]), bias/emlp -> f32 ----
__global__ __launch_bounds__(256) void k_cvt_par(const void* lw, const void* lb,
                                                 const void* emw, const void* emb,
                                                 unsigned short* __restrict__ wt,
                                                 float* lbf, float* emwf, float* embf,
                                                 const int* __restrict__ flags) {
  int i = blockIdx.x * 256 + threadIdx.x;
  const int bf = flags[0];
  if (i < NL * CC * CC) {
    unsigned short v = bf ? ((const unsigned short*)lw)[i]
                          : f2b(((const float*)lw)[i]);
    const int l = i >> 14, r = i & 16383, k = r >> 7, n = r & 127;
    wt[l * 16384 + n * 128 + k] = v;
  }
  if (i < NL * CC)
    lbf[i] = bf ? b2f(((const unsigned short*)lb)[i]) : ((const float*)lb)[i];
  if (i < NL * 8)
    emwf[i] = bf ? b2f(((const unsigned short*)emw)[i]) : ((const float*)emw)[i];
  if (i < NL)
    embf[i] = bf ? b2f(((const unsigned short*)emb)[i]) : ((const float*)emb)[i];
}

// ---- CSR build: histogram of dst ----
__global__ __launch_bounds__(256) void k_hist(const int* __restrict__ ei,
                                              int* __restrict__ deg,
                                              const int* __restrict__ flags) {
  int e = blockIdx.x * 256 + threadIdx.x;
  if (e >= NE) return;
  atomicAdd(&deg[eidx(ei, 1, e, flags[1])], 1);
}

// ---- 3-phase device-wide exclusive scan over deg[NN] ----
#define NI4 (NN / 4)
#define SCAN_BLKS ((NI4 + 255) / 256)   // 49
__global__ __launch_bounds__(256) void k_scan1(const int* __restrict__ deg,
                                               int* __restrict__ offs,
                                               int* __restrict__ bsum) {
  __shared__ int ls[256];
  const int t = threadIdx.x;
  const int g = blockIdx.x * 256 + t;
  int4 d = make_int4(0, 0, 0, 0);
  if (g < NI4) d = ((const int4*)deg)[g];
  const int s = d.x + d.y + d.z + d.w;
  ls[t] = s;
  __syncthreads();
#pragma unroll
  for (int off = 1; off < 256; off <<= 1) {
    int tmp = (t >= off) ? ls[t - off] : 0;
    __syncthreads();
    ls[t] += tmp;
    __syncthreads();
  }
  const int excl = ls[t] - s;
  if (g < NI4) {
    int4 o;
    o.x = excl; o.y = o.x + d.x; o.z = o.y + d.y; o.w = o.z + d.z;
    ((int4*)offs)[g] = o;
  }
  if (t == 255) bsum[blockIdx.x] = ls[255];
}

__global__ void k_scan2(const int* __restrict__ bsum, int* __restrict__ bbase,
                        int* __restrict__ offs) {
  if (threadIdx.x == 0) {
    int run = 0;
    for (int b = 0; b < SCAN_BLKS; ++b) { bbase[b] = run; run += bsum[b]; }
    offs[NN] = run;
  }
}

__global__ __launch_bounds__(256) void k_scan3(int* __restrict__ offs,
                                               int* __restrict__ cursor,
                                               const int* __restrict__ bbase) {
  const int g = blockIdx.x * 256 + threadIdx.x;
  if (g >= NI4) return;
  const int base = bbase[blockIdx.x];
  int4 o = ((int4*)offs)[g];
  o.x += base; o.y += base; o.z += base; o.w += base;
  ((int4*)offs)[g] = o;
  ((int4*)cursor)[g] = o;
}

// ---- CSR fill + all-layer edge weights, one scattered 16B store per edge:
//      esrt[pos] = (src, w0, w1, w2) with wl = softplus(ea . ew_l + eb_l)
__global__ __launch_bounds__(256) void k_fill2(const int* __restrict__ ei,
                                               const void* __restrict__ ea,
                                               const float* __restrict__ emwf,
                                               const float* __restrict__ embf,
                                               int* __restrict__ cursor,
                                               uint4* __restrict__ esrt,
                                               const int* __restrict__ flags) {
  int e = blockIdx.x * 256 + threadIdx.x;
  if (e >= NE) return;
  float a[8];
  if (flags[0]) {
    const uint4 v = ((const uint4*)ea)[e];
    unsigned int p[4] = {v.x, v.y, v.z, v.w};
#pragma unroll
    for (int q = 0; q < 4; ++q) {
      a[2 * q]     = __uint_as_float(p[q] << 16);
      a[2 * q + 1] = __uint_as_float(p[q] & 0xffff0000u);
    }
  } else {
    const float4 v0 = ((const float4*)ea)[2 * e];
    const float4 v1 = ((const float4*)ea)[2 * e + 1];
    a[0] = v0.x; a[1] = v0.y; a[2] = v0.z; a[3] = v0.w;
    a[4] = v1.x; a[5] = v1.y; a[6] = v1.z; a[7] = v1.w;
  }
  float w[NL];
#pragma unroll
  for (int l = 0; l < NL; ++l) {
    float z = embf[l];
#pragma unroll
    for (int k = 0; k < 8; ++k) z += a[k] * emwf[l * 8 + k];
    w[l] = (z > 20.f) ? z : log1pf(expf(z));
  }
  const int f64 = flags[1];
  const int d = eidx(ei, 1, e, f64);
  const int s = eidx(ei, 0, e, f64);
  const int pos = atomicAdd(&cursor[d], 1);
  esrt[pos] = make_uint4((unsigned)s, __float_as_uint(w[0]),
                         __float_as_uint(w[1]), __float_as_uint(w[2]));
}

// ---- gather (bf16): agg[n] = sum w*x[src] - (sum w)*x[n]; one wave/node.
// 8-edge straight-line unroll: 16 loads in flight per latency exposure.
__global__ __launch_bounds__(256) void k_gather(const int* __restrict__ offs,
                                                const uint4* __restrict__ esrt,
                                                const unsigned short* xb_,
                                                const unsigned short* alt,
                                                int sel, int layer,
                                                unsigned short* __restrict__ agg,
                                                const int* __restrict__ flags) {
  const unsigned short* xb = (sel && flags[0]) ? alt : xb_;
  const int node = blockIdx.x * 4 + (threadIdx.x >> 6);
  const int c = (threadIdx.x & 63) * 2;
  float ax = 0.f, ay = 0.f, sw = 0.f;
  int j = offs[node];
  const int j1 = offs[node + 1];
  for (; j + 8 <= j1; j += 8) {
    const uint4 p0 = esrt[j],     p1 = esrt[j + 1], p2 = esrt[j + 2], p3 = esrt[j + 3];
    const uint4 p4 = esrt[j + 4], p5 = esrt[j + 5], p6 = esrt[j + 6], p7 = esrt[j + 7];
    const unsigned v0 = *(const unsigned*)&xb[(size_t)p0.x * CC + c];
    const unsigned v1 = *(const unsigned*)&xb[(size_t)p1.x * CC + c];
    const unsigned v2 = *(const unsigned*)&xb[(size_t)p2.x * CC + c];
    const unsigned v3 = *(const unsigned*)&xb[(size_t)p3.x * CC + c];
    const unsigned v4 = *(const unsigned*)&xb[(size_t)p4.x * CC + c];
    const unsigned v5 = *(const unsigned*)&xb[(size_t)p5.x * CC + c];
    const unsigned v6 = *(const unsigned*)&xb[(size_t)p6.x * CC + c];
    const unsigned v7 = *(const unsigned*)&xb[(size_t)p7.x * CC + c];
    const float w0 = __uint_as_float(layer == 0 ? p0.y : (layer == 1 ? p0.z : p0.w));
    const float w1 = __uint_as_float(layer == 0 ? p1.y : (layer == 1 ? p1.z : p1.w));
    const float w2 = __uint_as_float(layer == 0 ? p2.y : (layer == 1 ? p2.z : p2.w));
    const float w3 = __uint_as_float(layer == 0 ? p3.y : (layer == 1 ? p3.z : p3.w));
    const float w4 = __uint_as_float(layer == 0 ? p4.y : (layer == 1 ? p4.z : p4.w));
    const float w5 = __uint_as_float(layer == 0 ? p5.y : (layer == 1 ? p5.z : p5.w));
    const float w6 = __uint_as_float(layer == 0 ? p6.y : (layer == 1 ? p6.z : p6.w));
    const float w7 = __uint_as_float(layer == 0 ? p7.y : (layer == 1 ? p7.z : p7.w));
    ax += w0 * __uint_as_float(v0 << 16) + w1 * __uint_as_float(v1 << 16)
        + w2 * __uint_as_float(v2 << 16) + w3 * __uint_as_float(v3 << 16)
        + w4 * __uint_as_float(v4 << 16) + w5 * __uint_as_float(v5 << 16)
        + w6 * __uint_as_float(v6 << 16) + w7 * __uint_as_float(v7 << 16);
    ay += w0 * __uint_as_float(v0 & 0xffff0000u) + w1 * __uint_as_float(v1 & 0xffff0000u)
        + w2 * __uint_as_float(v2 & 0xffff0000u) + w3 * __uint_as_float(v3 & 0xffff0000u)
        + w4 * __uint_as_float(v4 & 0xffff0000u) + w5 * __uint_as_float(v5 & 0xffff0000u)
        + w6 * __uint_as_float(v6 & 0xffff0000u) + w7 * __uint_as_float(v7 & 0xffff0000u);
    sw += w0 + w1 + w2 + w3 + w4 + w5 + w6 + w7;
  }
  for (; j + 4 <= j1; j += 4) {
    const uint4 p0 = esrt[j], p1 = esrt[j + 1], p2 = esrt[j + 2], p3 = esrt[j + 3];
    const float w0 = __uint_as_float(layer == 0 ? p0.y : (layer == 1 ? p0.z : p0.w));
    const float w1 = __uint_as_float(layer == 0 ? p1.y : (layer == 1 ? p1.z : p1.w));
    const float w2 = __uint_as_float(layer == 0 ? p2.y : (layer == 1 ? p2.z : p2.w));
    const float w3 = __uint_as_float(layer == 0 ? p3.y : (layer == 1 ? p3.z : p3.w));
    const unsigned v0 = *(const unsigned*)&xb[(size_t)p0.x * CC + c];
    const unsigned v1 = *(const unsigned*)&xb[(size_t)p1.x * CC + c];
    const unsigned v2 = *(const unsigned*)&xb[(size_t)p2.x * CC + c];
    const unsigned v3 = *(const unsigned*)&xb[(size_t)p3.x * CC + c];
    ax += w0 * __uint_as_float(v0 << 16) + w1 * __uint_as_float(v1 << 16)
        + w2 * __uint_as_float(v2 << 16) + w3 * __uint_as_float(v3 << 16);
    ay += w0 * __uint_as_float(v0 & 0xffff0000u) + w1 * __uint_as_float(v1 & 0xffff0000u)
        + w2 * __uint_as_float(v2 & 0xffff0000u) + w3 * __uint_as_float(v3 & 0xffff0000u);
    sw += w0 + w1 + w2 + w3;
  }
  for (; j < j1; ++j) {
    const uint4 p0 = esrt[j];
    const float w0 = __uint_as_float(layer == 0 ? p0.y : (layer == 1 ? p0.z : p0.w));
    const unsigned v0 = *(const unsigned*)&xb[(size_t)p0.x * CC + c];
    ax += w0 * __uint_as_float(v0 << 16);
    ay += w0 * __uint_as_float(v0 & 0xffff0000u);
    sw += w0;
  }
  const unsigned xi = *(const unsigned*)&xb[(size_t)node * CC + c];
  const float rx = ax - sw * __uint_as_float(xi << 16);
  const float ry = ay - sw * __uint_as_float(xi & 0xffff0000u);
  *(unsigned*)&agg[(size_t)node * CC + c] =
      (unsigned)f2b(rx) | ((unsigned)f2b(ry) << 16);
}

// ---- MFMA gemm: y = agg @ W + b; relu+residual -> in-place agg, or final store.
#define LPAD 136
__global__ __launch_bounds__(256) void k_gemm(unsigned short* agg,
                                              const unsigned short* xc_,
                                              const unsigned short* alt,
                                              int sel,
                                              const unsigned short* __restrict__ wt,
                                              const float* __restrict__ lbf,
                                              int layer, void* outp, int last,
                                              const int* __restrict__ flags) {
  const unsigned short* xc = (sel && flags[0]) ? alt : xc_;
  __shared__ unsigned short shA[64 * LPAD];    // 17408 B
  __shared__ unsigned short shB[128 * LPAD];   // 34816 B
  const int rb = blockIdx.x * 64;
  const unsigned short* wtl = wt + (size_t)layer * CC * CC;

  for (int u = threadIdx.x; u < 1024; u += 256) {        // A: 64 rows x 16 uint4
    const int row = u >> 4, q = u & 15;
    uint4 v = make_uint4(0, 0, 0, 0);
    if (rb + row < NN) v = *(const uint4*)&agg[(size_t)(rb + row) * CC + q * 8];
    *(uint4*)&shA[row * LPAD + q * 8] = v;
  }
  for (int u = threadIdx.x; u < 2048; u += 256) {        // B: 128 rows x 16 uint4
    const int row = u >> 4, q = u & 15;
    *(uint4*)&shB[row * LPAD + q * 8] = *(const uint4*)&wtl[row * 128 + q * 8];
  }
  __syncthreads();

  const int w = threadIdx.x >> 6;
  const int l = threadIdx.x & 63;
  const int lr = l & 15;
  const int lk = (l >> 4) * 8;

  U16 afr[4];
#pragma unroll
  for (int kk = 0; kk < 4; ++kk)
    afr[kk].u = *(const uint4*)&shA[(w * 16 + lr) * LPAD + kk * 32 + lk];

  const float* lbp = lbf + layer * CC;
  f32x4 acc[8];
#pragma unroll
  for (int t = 0; t < 8; ++t) {
    acc[t] = (f32x4){0.f, 0.f, 0.f, 0.f};
#pragma unroll
    for (int kk = 0; kk < 4; ++kk) {
      U16 bfr;
      bfr.u = *(const uint4*)&shB[(t * 16 + lr) * LPAD + kk * 32 + lk];
      acc[t] = __builtin_amdgcn_mfma_f32_16x16x32_bf16(afr[kk].v, bfr.v, acc[t], 0, 0, 0);
    }
  }

#pragma unroll
  for (int t = 0; t < 8; ++t) {
    const float bv = lbp[t * 16 + lr];
#pragma unroll
    for (int r = 0; r < 4; ++r) {
      const int tr = (l >> 4) * 4 + r;   // C/D: row = quad*4 + reg
      shA[(w * 16 + tr) * LPAD + t * 16 + lr] = f2b(acc[t][r] + bv);
    }
  }
  const int isbf = flags[0];
#pragma unroll
  for (int i = 0; i < 8; ++i) {
    const int idx = i * 64 + l;
    const int row = idx >> 5, cg = idx & 31;
    const int gr = rb + w * 16 + row;
    if (gr >= NN) continue;
    const uint2 yv = *(const uint2*)&shA[(w * 16 + row) * LPAD + cg * 4];
    float y0 = __uint_as_float(yv.x << 16);
    float y1 = __uint_as_float(yv.x & 0xffff0000u);
    float y2 = __uint_as_float(yv.y << 16);
    float y3 = __uint_as_float(yv.y & 0xffff0000u);
    const size_t off = (size_t)gr * CC + cg * 4;
    if (!last) {
      const uint2 rv = *(const uint2*)&xc[off];
      y0 = fmaxf(y0, 0.f) + __uint_as_float(rv.x << 16);
      y1 = fmaxf(y1, 0.f) + __uint_as_float(rv.x & 0xffff0000u);
      y2 = fmaxf(y2, 0.f) + __uint_as_float(rv.y << 16);
      y3 = fmaxf(y3, 0.f) + __uint_as_float(rv.y & 0xffff0000u);
      *(uint2*)&agg[off] = make_uint2((unsigned)f2b(y0) | ((unsigned)f2b(y1) << 16),
                                      (unsigned)f2b(y2) | ((unsigned)f2b(y3) << 16));
    } else if (isbf) {
      *(uint2*)&((unsigned short*)outp)[off] = yv;
    } else {
      *(float4*)&((float*)outp)[off] = make_float4(y0, y1, y2, y3);
    }
  }
}

extern "C" void kernel_launch(void* const* d_in, const int* in_sizes, int n_in,
                              void* d_out, int out_size, void* d_ws, size_t ws_size,
                              hipStream_t stream) {
  const unsigned short* x0 = (const unsigned short*)d_in[0];
  const int* ei = (const int*)d_in[1];

  const size_t nbuf = (size_t)NN * CC;
  unsigned short* xb0 = (unsigned short*)d_ws;
  unsigned short* xb1 = xb0 + nbuf;
  unsigned short* wt = xb1 + nbuf;
  uint4* esrt = (uint4*)(wt + (size_t)NL * CC * CC);
  int* deg = (int*)(esrt + NE);
  int* offs = deg + NN;
  int* cursor = offs + NN + 4;
  int* bsum = cursor + NN;
  int* bbase = bsum + 64;
  float* lbf = (float*)(bbase + 64);
  float* emwf = lbf + (size_t)NL * CC;
  float* embf = emwf + NL * 8;
  int* flags = (int*)(embf + NL);
  const size_t need = (size_t)((char*)(flags + 2) - (char*)d_ws);
  if (ws_size < need) {
    hipMemsetAsync(d_out, 0, (size_t)out_size * 2, stream);
    return;
  }

  k_flags<<<1, 256, 0, stream>>>(x0, ei, flags);
  k_cvt_x<<<(NN * CC / 8) / 256, 256, 0, stream>>>(d_in[0], xb0, flags);
  k_cvt_par<<<(NL * CC * CC + 255) / 256, 256, 0, stream>>>(
      d_in[3], d_in[4], d_in[5], d_in[6], wt, lbf, emwf, embf, flags);

  hipMemsetAsync(deg, 0, NN * sizeof(int), stream);
  k_hist<<<(NE + 255) / 256, 256, 0, stream>>>(ei, deg, flags);
  k_scan1<<<SCAN_BLKS, 256, 0, stream>>>(deg, offs, bsum);
  k_scan2<<<1, 64, 0, stream>>>(bsum, bbase, offs);
  k_scan3<<<SCAN_BLKS, 256, 0, stream>>>(offs, cursor, bbase);
  k_fill2<<<(NE + 255) / 256, 256, 0, stream>>>(ei, d_in[2], emwf, embf,
                                                cursor, esrt, flags);

  unsigned short* xc = xb0;
  unsigned short* ag = xb1;
  for (int layer = 0; layer < NL; ++layer) {
    const int sel = (layer == 0) ? 1 : 0;
    k_gather<<<NN / 4, 256, 0, stream>>>(offs, esrt, xc, x0, sel, layer, ag, flags);
    k_gemm<<<(NN + 63) / 64, 256, 0, stream>>>(ag, xc, x0, sel, wt, lbf, layer,
                                               d_out, layer == NL - 1 ? 1 : 0, flags);
    unsigned short* t = xc; xc = ag; ag = t;   // gemm wrote new x into ag
  }
}